// Round 7
// baseline (731.820 us; speedup 1.0000x reference)
//
#include <hip/hip_runtime.h>
#include <hip/hip_bf16.h>

// ---------------------------------------------------------------------------
// GCN via agg-commute: agg(XW) == agg(X)W. z = dinv (.) h stored bf16.
// Fused layer: A_i = dinv_i(sum z[src] + z[i]) -> LDS -> MFMA A@W -> +b, relu,
// x dinv -> bf16. Layer3: P = z2@W3, then agg64 fused with mean-pool.
// R7: degree-sorted node permutation for the fused layers (R6 counters:
//     occupancy 52->33%, BW 3.56->2.71 TB/s from the pre-MFMA barrier waiting
//     on the block's max-degree node). Blocks now uniform-degree.
// ---------------------------------------------------------------------------

#define THREADS 256
#define BSHIFT 9
#define BSIZE 512

typedef __attribute__((ext_vector_type(8))) short short8;
typedef __attribute__((ext_vector_type(16))) float floatx16;

__device__ __forceinline__ unsigned f2bf(float f) {  // fp32 -> bf16 bits, RNE
    unsigned u = __float_as_uint(f);
    return (u + 0x7fffu + ((u >> 16) & 1u)) >> 16;
}

__device__ __forceinline__ void bf8_acc(uint4 v, float* ac) {
    ac[0] += __uint_as_float(v.x << 16);
    ac[1] += __uint_as_float(v.x & 0xffff0000u);
    ac[2] += __uint_as_float(v.y << 16);
    ac[3] += __uint_as_float(v.y & 0xffff0000u);
    ac[4] += __uint_as_float(v.z << 16);
    ac[5] += __uint_as_float(v.z & 0xffff0000u);
    ac[6] += __uint_as_float(v.w << 16);
    ac[7] += __uint_as_float(v.w & 0xffff0000u);
}

// ---- bucketed CSR build ----------------------------------------------------

__global__ __launch_bounds__(THREADS) void bucket_count(const int* __restrict__ dst,
                                                        int* __restrict__ btotal,
                                                        int E, int nbuck) {
    __shared__ int cnt[BSIZE];
    for (int i = threadIdx.x; i < nbuck; i += THREADS) cnt[i] = 0;
    __syncthreads();
    for (int e = blockIdx.x * THREADS + threadIdx.x; e < E; e += gridDim.x * THREADS)
        atomicAdd(&cnt[dst[e] >> BSHIFT], 1);
    __syncthreads();
    for (int i = threadIdx.x; i < nbuck; i += THREADS) {
        int c = cnt[i];
        if (c) atomicAdd(&btotal[i], c);
    }
}

__global__ __launch_bounds__(512) void bucket_scan(const int* __restrict__ btotal,
                                                   int* __restrict__ bbase,
                                                   int* __restrict__ bcursor,
                                                   int nbuck, int E) {
    __shared__ int lds[512];
    int t = threadIdx.x;
    int v = (t < nbuck) ? btotal[t] : 0;
    lds[t] = v;
    __syncthreads();
    for (int off = 1; off < 512; off <<= 1) {
        int tv = (t >= off) ? lds[t - off] : 0;
        __syncthreads();
        lds[t] += tv;
        __syncthreads();
    }
    if (t < nbuck) {
        int excl = lds[t] - v;
        bbase[t] = excl;
        bcursor[t] = excl;
    }
    if (t == 0) bbase[nbuck] = E;
}

__global__ __launch_bounds__(THREADS) void bucket_scatter(const int* __restrict__ src,
                                                          const int* __restrict__ dst,
                                                          int* __restrict__ bcursor,
                                                          int2* __restrict__ pairs, int E) {
    __shared__ int cnt[BSIZE];
    __shared__ int base[BSIZE];
    for (int i = threadIdx.x; i < BSIZE; i += THREADS) cnt[i] = 0;
    __syncthreads();
    int e0 = blockIdx.x * 2048;
    int myb[8], myrank[8], mysrc[8], mydst[8];
#pragma unroll
    for (int j = 0; j < 8; ++j) {
        int e = e0 + j * THREADS + threadIdx.x;
        myb[j] = -1;
        if (e < E) {
            int d = dst[e];
            mysrc[j] = src[e];
            mydst[j] = d;
            myb[j] = d >> BSHIFT;
            myrank[j] = atomicAdd(&cnt[myb[j]], 1);
        }
    }
    __syncthreads();
    for (int i = threadIdx.x; i < BSIZE; i += THREADS) {
        int c = cnt[i];
        base[i] = c ? atomicAdd(&bcursor[i], c) : 0;
    }
    __syncthreads();
#pragma unroll
    for (int j = 0; j < 8; ++j)
        if (myb[j] >= 0) pairs[(size_t)base[myb[j]] + myrank[j]] = make_int2(mysrc[j], mydst[j]);
}

__global__ __launch_bounds__(512) void bucket_fill(const int2* __restrict__ pairs,
                                                   const int* __restrict__ bbase,
                                                   int* __restrict__ row_start,
                                                   float* __restrict__ dinv,
                                                   int* __restrict__ esrc,
                                                   int N, int E, int nbuck) {
    __shared__ int cnt[BSIZE];
    __shared__ int scn[BSIZE];
    int b = blockIdx.x, t = threadIdx.x;
    int s = bbase[b], e = bbase[b + 1];
    cnt[t] = 0;
    __syncthreads();
    for (int i = s + t; i < e; i += 512) atomicAdd(&cnt[pairs[i].y & (BSIZE - 1)], 1);
    __syncthreads();
    int v = cnt[t];
    scn[t] = v;
    __syncthreads();
    for (int off = 1; off < 512; off <<= 1) {
        int tv = (t >= off) ? scn[t - off] : 0;
        __syncthreads();
        scn[t] += tv;
        __syncthreads();
    }
    int excl = scn[t] - v;
    int g = (b << BSHIFT) + t;
    if (g < N) {
        row_start[g] = s + excl;
        dinv[g] = rsqrtf(1.0f + (float)v);  // deg = 1 + in-degree (self-loop)
    }
    if (b == nbuck - 1 && t == 0) row_start[N] = E;
    scn[t] = excl;  // reuse as cursor
    __syncthreads();
    for (int i = s + t; i < e; i += 512) {
        int2 p = pairs[i];
        int r = atomicAdd(&scn[p.y & (BSIZE - 1)], 1);
        esrc[s + r] = p.x;
    }
}

// ---- degree-sorted permutation (counting sort, 256 degree classes) ---------
__global__ __launch_bounds__(THREADS) void deg_hist(const int* __restrict__ row_start,
                                                    int* __restrict__ hist, int N) {
    __shared__ int h[256];
    h[threadIdx.x] = 0;
    __syncthreads();
    int i = blockIdx.x * THREADS + threadIdx.x;
    if (i < N) {
        int d = min(row_start[i + 1] - row_start[i], 255);
        atomicAdd(&h[d], 1);
    }
    __syncthreads();
    int c = h[threadIdx.x];
    if (c) atomicAdd(&hist[threadIdx.x], c);
}

__global__ __launch_bounds__(256) void deg_scan(const int* __restrict__ hist,
                                                int* __restrict__ dcur) {
    __shared__ int lds[256];
    int t = threadIdx.x;
    int v = hist[t];
    lds[t] = v;
    __syncthreads();
    for (int off = 1; off < 256; off <<= 1) {
        int tv = (t >= off) ? lds[t - off] : 0;
        __syncthreads();
        lds[t] += tv;
        __syncthreads();
    }
    dcur[t] = lds[t] - v;  // exclusive
}

__global__ __launch_bounds__(THREADS) void perm_scatter(const int* __restrict__ row_start,
                                                        int* __restrict__ dcur,
                                                        int* __restrict__ perm, int N) {
    int i = blockIdx.x * THREADS + threadIdx.x;
    if (i < N) {
        int d = min(row_start[i + 1] - row_start[i], 255);
        int pos = atomicAdd(&dcur[d], 1);
        perm[pos] = i;
    }
}

// ---- prep: all three W^T (bf16 packed) in one launch -----------------------
__device__ __forceinline__ void wt_pack(const float* W, uint4* Wtp, int C, int li) {
    int c = li >> 4, ch = li & 15;
    unsigned r[8];
#pragma unroll
    for (int j = 0; j < 8; ++j) r[j] = f2bf(W[(size_t)(ch * 8 + j) * C + c]);
    uint4 o;
    o.x = r[0] | (r[1] << 16);
    o.y = r[2] | (r[3] << 16);
    o.z = r[4] | (r[5] << 16);
    o.w = r[6] | (r[7] << 16);
    Wtp[li] = o;
}

__global__ __launch_bounds__(THREADS) void prep_wt_all(const float* __restrict__ W1,
                                                       const float* __restrict__ W2,
                                                       const float* __restrict__ W3,
                                                       uint4* __restrict__ Wt1,
                                                       uint4* __restrict__ Wt2,
                                                       uint4* __restrict__ Wt3) {
    int idx = blockIdx.x * THREADS + threadIdx.x;
    if (idx < 2048) wt_pack(W1, Wt1, 128, idx);
    else if (idx < 4096) wt_pack(W2, Wt2, 128, idx - 2048);
    else if (idx < 5120) wt_pack(W3, Wt3, 64, idx - 4096);
}

// ---- prep: z1 = bf16(dinv (.) x) -------------------------------------------
__global__ __launch_bounds__(THREADS) void prep_x(const float* __restrict__ x,
                                                  const float* __restrict__ dinv,
                                                  uint4* __restrict__ Z, int n) {
    int idx = blockIdx.x * THREADS + threadIdx.x;  // r*16 + chunk
    if (idx >= n * 16) return;
    int r = idx >> 4, c = idx & 15;
    float dv = dinv[r];
    const float* p = x + (size_t)r * 128 + c * 8;
    float4 a = *(const float4*)p;
    float4 b = *(const float4*)(p + 4);
    uint4 o;
    o.x = f2bf(a.x * dv) | (f2bf(a.y * dv) << 16);
    o.y = f2bf(a.z * dv) | (f2bf(a.w * dv) << 16);
    o.z = f2bf(b.x * dv) | (f2bf(b.y * dv) << 16);
    o.w = f2bf(b.z * dv) | (f2bf(b.w * dv) << 16);
    Z[idx] = o;
}

// ---- fused layer (perm order): gather -> LDS -> MFMA -> epilogue -----------
__global__ __launch_bounds__(THREADS) void fused_layer(const uint4* __restrict__ Z,
                                                       const uint4* __restrict__ Wt,
                                                       const int* __restrict__ row_start,
                                                       const int* __restrict__ esrc,
                                                       const float* __restrict__ dinv,
                                                       const float* __restrict__ bias,
                                                       const int* __restrict__ perm,
                                                       uint4* __restrict__ out, int n) {
    __shared__ __align__(16) uint4 ldsX[64 * 16];  // 16KB: A-tile, reused for out-stage
    __shared__ int nodes_s[64];
    int row0 = blockIdx.x * 64;
    int tid = threadIdx.x;
    int lane = tid & 15, grp = tid >> 4;

    // ---- gather phase: 16 lanes/node, 16 nodes concurrent, 4 rounds ----
    for (int round = 0; round < 4; ++round) {
        int r = round * 16 + grp;
        int gi = row0 + r;
        int nd = perm[(gi < n) ? gi : (n - 1)];  // uniform-degree within block
        if (lane == 0) nodes_s[r] = nd;
        float ac[8] = {0, 0, 0, 0, 0, 0, 0, 0};
        bf8_acc(Z[(size_t)nd * 16 + lane], ac);  // self term z[i]
        int s = row_start[nd], e = row_start[nd + 1];
        int i = s;
        for (; i + 8 <= e; i += 8) {
            int s0 = esrc[i], s1 = esrc[i + 1], s2 = esrc[i + 2], s3 = esrc[i + 3];
            int s4 = esrc[i + 4], s5 = esrc[i + 5], s6 = esrc[i + 6], s7 = esrc[i + 7];
            uint4 v0 = Z[(size_t)s0 * 16 + lane];
            uint4 v1 = Z[(size_t)s1 * 16 + lane];
            uint4 v2 = Z[(size_t)s2 * 16 + lane];
            uint4 v3 = Z[(size_t)s3 * 16 + lane];
            uint4 v4 = Z[(size_t)s4 * 16 + lane];
            uint4 v5 = Z[(size_t)s5 * 16 + lane];
            uint4 v6 = Z[(size_t)s6 * 16 + lane];
            uint4 v7 = Z[(size_t)s7 * 16 + lane];
            bf8_acc(v0, ac); bf8_acc(v1, ac); bf8_acc(v2, ac); bf8_acc(v3, ac);
            bf8_acc(v4, ac); bf8_acc(v5, ac); bf8_acc(v6, ac); bf8_acc(v7, ac);
        }
        for (; i + 4 <= e; i += 4) {
            int s0 = esrc[i], s1 = esrc[i + 1], s2 = esrc[i + 2], s3 = esrc[i + 3];
            uint4 v0 = Z[(size_t)s0 * 16 + lane];
            uint4 v1 = Z[(size_t)s1 * 16 + lane];
            uint4 v2 = Z[(size_t)s2 * 16 + lane];
            uint4 v3 = Z[(size_t)s3 * 16 + lane];
            bf8_acc(v0, ac); bf8_acc(v1, ac); bf8_acc(v2, ac); bf8_acc(v3, ac);
        }
        for (; i < e; ++i) bf8_acc(Z[(size_t)esrc[i] * 16 + lane], ac);
        float dv = dinv[nd];  // A_i = dinv_i * (sum z[src] + z[i])
        uint4 o;
        o.x = f2bf(ac[0] * dv) | (f2bf(ac[1] * dv) << 16);
        o.y = f2bf(ac[2] * dv) | (f2bf(ac[3] * dv) << 16);
        o.z = f2bf(ac[4] * dv) | (f2bf(ac[5] * dv) << 16);
        o.w = f2bf(ac[6] * dv) | (f2bf(ac[7] * dv) << 16);
        ldsX[r * 16 + (lane ^ (r & 7))] = o;
    }
    __syncthreads();

    // ---- MFMA phase: D = W^T A^T ; W read from L2-hot global ----
    int l = tid & 63, wv = tid >> 6;
    int l31 = l & 31, half = l >> 5;
    int nt = wv & 1, mt0 = (wv >> 1) * 2;
    floatx16 acc[2];
#pragma unroll
    for (int t = 0; t < 2; ++t)
#pragma unroll
        for (int q = 0; q < 16; ++q) acc[t][q] = 0.0f;
    int xrow = nt * 32 + l31, xsw = xrow & 7;
#pragma unroll
    for (int kt = 0; kt < 8; ++kt) {
        int chunk = kt * 2 + half;
        short8 xf = *(const short8*)&ldsX[xrow * 16 + (chunk ^ xsw)];
#pragma unroll
        for (int t = 0; t < 2; ++t) {
            int c = (mt0 + t) * 32 + l31;
            short8 wf = *(const short8*)&Wt[c * 16 + chunk];
            acc[t] = __builtin_amdgcn_mfma_f32_32x32x16_bf16(wf, xf, acc[t], 0, 0, 0);
        }
    }
    __syncthreads();

    // ---- epilogue: +bias, relu, x dinv(node), pack bf16 -> LDS ----
    int lrow = nt * 32 + l31;  // local row
    float dv = (row0 + lrow < n) ? dinv[nodes_s[lrow]] : 0.0f;
    char* outb = (char*)ldsX;
#pragma unroll
    for (int t = 0; t < 2; ++t) {
        int cb = (mt0 + t) * 32;
#pragma unroll
        for (int q = 0; q < 4; ++q) {
            float v[4];
#pragma unroll
            for (int m = 0; m < 4; ++m) {
                int ch = cb + 8 * q + 4 * half + m;
                float x_ = acc[t][q * 4 + m] + bias[ch];
                x_ = fmaxf(x_, 0.0f);  // relu (both fused layers use it)
                v[m] = x_ * dv;        // pre-scale for next layer's gather
            }
            uint2 pk = make_uint2(f2bf(v[0]) | (f2bf(v[1]) << 16),
                                  f2bf(v[2]) | (f2bf(v[3]) << 16));
            int chunk = (cb >> 3) + q;
            *(uint2*)(outb + lrow * 256 + ((chunk ^ (lrow & 7)) * 16) + half * 8) = pk;
        }
    }
    __syncthreads();
    int maxr = n - row0;
    if (maxr > 64) maxr = 64;
    for (int idx = tid; idx < maxr * 16; idx += THREADS) {
        int r = idx >> 4, c = idx & 15;
        out[(size_t)nodes_s[r] * 16 + c] = *(uint4*)(outb + r * 256 + ((c ^ (r & 7)) * 16));
    }
}

// ---- layer-3 GEMM: Ps = Z2 @ W3 (128 -> 64ch) ------------------------------
__global__ __launch_bounds__(THREADS) void gemm3(const uint4* __restrict__ Z,
                                                 const uint4* __restrict__ Wt,
                                                 uint4* __restrict__ out, int n) {
    __shared__ __align__(16) uint4 ldsX[64 * 16];  // 16KB
    int row0 = blockIdx.x * 64;
    int maxr = n - row0;
    if (maxr > 64) maxr = 64;
    int tid = threadIdx.x;
    for (int idx = tid; idx < 1024; idx += THREADS) {
        int r = idx >> 4, c = idx & 15;
        uint4 o = (r < maxr) ? Z[(size_t)(row0 + r) * 16 + c] : make_uint4(0, 0, 0, 0);
        ldsX[r * 16 + (c ^ (r & 7))] = o;
    }
    __syncthreads();
    int l = tid & 63, wv = tid >> 6;
    int l31 = l & 31, half = l >> 5;
    int nt = wv & 1, mt = wv >> 1;
    floatx16 acc;
#pragma unroll
    for (int q = 0; q < 16; ++q) acc[q] = 0.0f;
    int xrow = nt * 32 + l31, xsw = xrow & 7;
#pragma unroll
    for (int kt = 0; kt < 8; ++kt) {
        int chunk = kt * 2 + half;
        short8 xf = *(const short8*)&ldsX[xrow * 16 + (chunk ^ xsw)];
        int c = mt * 32 + l31;
        short8 wf = *(const short8*)&Wt[c * 16 + chunk];
        acc = __builtin_amdgcn_mfma_f32_32x32x16_bf16(wf, xf, acc, 0, 0, 0);
    }
    __syncthreads();
    int node = nt * 32 + l31;
    char* outb = (char*)ldsX;  // 64 rows x 128B
    int cb = mt * 32;
#pragma unroll
    for (int q = 0; q < 4; ++q) {
        uint2 pk = make_uint2(f2bf(acc[q * 4 + 0]) | (f2bf(acc[q * 4 + 1]) << 16),
                              f2bf(acc[q * 4 + 2]) | (f2bf(acc[q * 4 + 3]) << 16));
        int chunk = (cb >> 3) + q;
        *(uint2*)(outb + node * 128 + ((chunk ^ (node & 7)) * 16) + half * 8) = pk;
    }
    __syncthreads();
    for (int idx = tid; idx < maxr * 8; idx += THREADS) {
        int r = idx >> 3, c = idx & 7;
        out[(size_t)(row0 + r) * 8 + c] = *(uint4*)(outb + r * 128 + ((c ^ (r & 7)) * 16));
    }
}

// ---- layer-3 agg fused with mean-pool accumulation (natural node order) ----
__global__ __launch_bounds__(THREADS) void agg_pool(const uint4* __restrict__ Ps,
                                                    const int* __restrict__ row_start,
                                                    const int* __restrict__ esrc,
                                                    const float* __restrict__ dinv,
                                                    const float* __restrict__ bias,
                                                    const int* __restrict__ batch,
                                                    float* __restrict__ gsum, int n) {
    __shared__ float gpart[32][65];  // pad 65: lanes hit distinct banks
    __shared__ int used[32];
    int tid = threadIdx.x;
    int lane = tid & 7, grp = tid >> 3;
    int node = blockIdx.x * 32 + grp;
    if (tid < 32) used[tid] = 0;
    for (int idx = tid; idx < 2048; idx += THREADS) gpart[idx >> 6][idx & 63] = 0.0f;
    __syncthreads();
    int gmin = batch[blockIdx.x * 32];  // block's first node is always < n
    if (node < n) {
        float ac[8] = {0, 0, 0, 0, 0, 0, 0, 0};
        bf8_acc(Ps[(size_t)node * 8 + lane], ac);  // self
        int s = row_start[node], e = row_start[node + 1];
        int i = s;
        for (; i + 8 <= e; i += 8) {
            int s0 = esrc[i], s1 = esrc[i + 1], s2 = esrc[i + 2], s3 = esrc[i + 3];
            int s4 = esrc[i + 4], s5 = esrc[i + 5], s6 = esrc[i + 6], s7 = esrc[i + 7];
            uint4 v0 = Ps[(size_t)s0 * 8 + lane];
            uint4 v1 = Ps[(size_t)s1 * 8 + lane];
            uint4 v2 = Ps[(size_t)s2 * 8 + lane];
            uint4 v3 = Ps[(size_t)s3 * 8 + lane];
            uint4 v4 = Ps[(size_t)s4 * 8 + lane];
            uint4 v5 = Ps[(size_t)s5 * 8 + lane];
            uint4 v6 = Ps[(size_t)s6 * 8 + lane];
            uint4 v7 = Ps[(size_t)s7 * 8 + lane];
            bf8_acc(v0, ac); bf8_acc(v1, ac); bf8_acc(v2, ac); bf8_acc(v3, ac);
            bf8_acc(v4, ac); bf8_acc(v5, ac); bf8_acc(v6, ac); bf8_acc(v7, ac);
        }
        for (; i + 4 <= e; i += 4) {
            int s0 = esrc[i], s1 = esrc[i + 1], s2 = esrc[i + 2], s3 = esrc[i + 3];
            uint4 v0 = Ps[(size_t)s0 * 8 + lane];
            uint4 v1 = Ps[(size_t)s1 * 8 + lane];
            uint4 v2 = Ps[(size_t)s2 * 8 + lane];
            uint4 v3 = Ps[(size_t)s3 * 8 + lane];
            bf8_acc(v0, ac); bf8_acc(v1, ac); bf8_acc(v2, ac); bf8_acc(v3, ac);
        }
        for (; i < e; ++i) bf8_acc(Ps[(size_t)esrc[i] * 8 + lane], ac);
        float dv = dinv[node];
        float4 b0 = ((const float4*)bias)[lane * 2];
        float4 b1 = ((const float4*)bias)[lane * 2 + 1];
        float h[8];
        h[0] = fmaf(dv, ac[0], b0.x); h[1] = fmaf(dv, ac[1], b0.y);
        h[2] = fmaf(dv, ac[2], b0.z); h[3] = fmaf(dv, ac[3], b0.w);
        h[4] = fmaf(dv, ac[4], b1.x); h[5] = fmaf(dv, ac[5], b1.y);
        h[6] = fmaf(dv, ac[6], b1.z); h[7] = fmaf(dv, ac[7], b1.w);
        int g = batch[node];
        int slot = g - gmin;
        if (slot < 32) {
            if (lane == 0) used[slot] = 1;
#pragma unroll
            for (int j = 0; j < 8; ++j) atomicAdd(&gpart[slot][lane * 8 + j], h[j]);
        } else {  // only possible with empty graphs between nodes
#pragma unroll
            for (int j = 0; j < 8; ++j) atomicAdd(&gsum[(size_t)g * 64 + lane * 8 + j], h[j]);
        }
    }
    __syncthreads();
    for (int idx = tid; idx < 2048; idx += THREADS) {
        int s = idx >> 6, ch = idx & 63;
        if (used[s]) atomicAdd(&gsum[(size_t)(gmin + s) * 64 + ch], gpart[s][ch]);
    }
}

// ---- finalize: mean + FC ---------------------------------------------------
__device__ __forceinline__ int dev_lower_bound(const int* a, int n, int key) {
    int lo = 0, hi = n;
    while (lo < hi) {
        int mid = (lo + hi) >> 1;
        if (a[mid] < key) lo = mid + 1;
        else hi = mid;
    }
    return lo;
}

__global__ __launch_bounds__(128) void finalize_fc(const float* __restrict__ gsum,
                                                   const int* __restrict__ batch, int n,
                                                   const float* __restrict__ Wfc,
                                                   const float* __restrict__ bfc,
                                                   float* __restrict__ out) {
    __shared__ float gm[64 * 64];
    __shared__ float cnt[64];
    int t = threadIdx.x;
    if (t < 64)
        cnt[t] = (float)(dev_lower_bound(batch, n, t + 1) - dev_lower_bound(batch, n, t));
    __syncthreads();
    for (int i = t; i < 64 * 64; i += 128) gm[i] = gsum[i] / fmaxf(cnt[i >> 6], 1.0f);
    __syncthreads();
    int g = t >> 1, cls = t & 1;
    float acc = bfc[cls];
    for (int c = 0; c < 64; ++c) acc = fmaf(gm[g * 64 + c], Wfc[c * 2 + cls], acc);
    out[g * 2 + cls] = acc;
}

extern "C" void kernel_launch(void* const* d_in, const int* in_sizes, int n_in,
                              void* d_out, int out_size, void* d_ws, size_t ws_size,
                              hipStream_t stream) {
    const float* x    = (const float*)d_in[0];
    const int*   ei   = (const int*)d_in[1];
    const int*   batch= (const int*)d_in[2];
    const float* W1   = (const float*)d_in[3];
    const float* b1   = (const float*)d_in[4];
    const float* W2   = (const float*)d_in[5];
    const float* b2   = (const float*)d_in[6];
    const float* W3   = (const float*)d_in[7];
    const float* b3   = (const float*)d_in[8];
    const float* Wfc  = (const float*)d_in[9];
    const float* bfc  = (const float*)d_in[10];
    float* out = (float*)d_out;

    const int N = in_sizes[2];        // 100000
    const int E = in_sizes[1] / 2;    // 1600000
    const int* esrc_in = ei;          // edge_index[0]
    const int* edst_in = ei + E;      // edge_index[1]
    const int nbuck = (N + BSIZE - 1) >> BSHIFT;  // 196

    // workspace layout (~85 MB)
    uint4* bufA      = (uint4*)d_ws;                  // N*16 uint4 (z, bf16 packed)
    uint4* bufB      = bufA + (size_t)N * 16;         // N*16 uint4
    uint4* bufC      = bufB + (size_t)N * 16;         // N*8 uint4 (Ps)
    int2*  pairs     = (int2*)(bufC + (size_t)N * 8); // E
    int*   esrc      = (int*)(pairs + E);             // E
    int*   row_start = esrc + E;                      // N+1
    float* dinv      = (float*)(row_start + N + 1);   // N
    int*   perm      = (int*)(dinv + N);              // N
    int*   btotal    = perm + N;                      // 512
    int*   bbase     = btotal + 512;                  // 513
    int*   bcursor   = bbase + 513;                   // 512
    int*   dhist     = bcursor + 512;                 // 256
    int*   dcur      = dhist + 256;                   // 256
    float* gsum      = (float*)(dcur + 256);          // 64*64
    uint4* Wt1       = (uint4*)(gsum + 64 * 64);      // 2048
    uint4* Wt2       = Wt1 + 2048;                    // 2048
    uint4* Wt3       = Wt2 + 2048;                    // 1024

    // ---- CSR build + perm + prep ----
    hipMemsetAsync(btotal, 0, 512 * sizeof(int), stream);
    hipMemsetAsync(dhist, 0, 256 * sizeof(int), stream);
    hipMemsetAsync(gsum, 0, 64 * 64 * sizeof(float), stream);
    bucket_count<<<512, THREADS, 0, stream>>>(edst_in, btotal, E, nbuck);
    bucket_scan<<<1, 512, 0, stream>>>(btotal, bbase, bcursor, nbuck, E);
    bucket_scatter<<<(E + 2047) / 2048, THREADS, 0, stream>>>(esrc_in, edst_in, bcursor, pairs, E);
    bucket_fill<<<nbuck, 512, 0, stream>>>(pairs, bbase, row_start, dinv, esrc, N, E, nbuck);
    deg_hist<<<(N + THREADS - 1) / THREADS, THREADS, 0, stream>>>(row_start, dhist, N);
    deg_scan<<<1, 256, 0, stream>>>(dhist, dcur);
    perm_scatter<<<(N + THREADS - 1) / THREADS, THREADS, 0, stream>>>(row_start, dcur, perm, N);
    prep_wt_all<<<20, THREADS, 0, stream>>>(W1, W2, W3, Wt1, Wt2, Wt3);
    prep_x<<<(N * 16 + THREADS - 1) / THREADS, THREADS, 0, stream>>>(x, dinv, bufA, N);

    const int GB = (N + 63) / 64;

    // ---- layers (agg-commuted, degree-balanced) ----
    fused_layer<<<GB, THREADS, 0, stream>>>(bufA, Wt1, row_start, esrc, dinv, b1, perm, bufB, N);
    fused_layer<<<GB, THREADS, 0, stream>>>(bufB, Wt2, row_start, esrc, dinv, b2, perm, bufA, N);
    gemm3<<<GB, THREADS, 0, stream>>>(bufA, Wt3, bufC, N);
    agg_pool<<<(N + 31) / 32, THREADS, 0, stream>>>(bufC, row_start, esrc, dinv, b3, batch, gsum, N);

    // ---- finalize ----
    finalize_fc<<<1, 128, 0, stream>>>(gsum, batch, N, Wfc, bfc, out);
}

// Round 8
// 443.740 us; speedup vs baseline: 1.6492x; 1.6492x over previous
//
#include <hip/hip_runtime.h>
#include <hip/hip_bf16.h>

// ---------------------------------------------------------------------------
// GCN via agg-commute: agg(XW) == agg(X)W. z = dinv (.) h stored bf16.
// Fused layer: A_i = dinv_i(sum z[src] + z[i]) -> LDS -> MFMA A@W -> +b, relu,
// x dinv -> bf16. Layer3: P = z2@W3, then agg64 fused with mean-pool.
// R8: contention-free counting sort for the degree perm (R7's perm_scatter
//     was 281us: 100K value-returning atomics on 4 cache lines) + DESCENDING
//     degree order (LPT: heavy blocks dispatch first, light ones backfill).
// ---------------------------------------------------------------------------

#define THREADS 256
#define BSHIFT 9
#define BSIZE 512

typedef __attribute__((ext_vector_type(8))) short short8;
typedef __attribute__((ext_vector_type(16))) float floatx16;

__device__ __forceinline__ unsigned f2bf(float f) {  // fp32 -> bf16 bits, RNE
    unsigned u = __float_as_uint(f);
    return (u + 0x7fffu + ((u >> 16) & 1u)) >> 16;
}

__device__ __forceinline__ void bf8_acc(uint4 v, float* ac) {
    ac[0] += __uint_as_float(v.x << 16);
    ac[1] += __uint_as_float(v.x & 0xffff0000u);
    ac[2] += __uint_as_float(v.y << 16);
    ac[3] += __uint_as_float(v.y & 0xffff0000u);
    ac[4] += __uint_as_float(v.z << 16);
    ac[5] += __uint_as_float(v.z & 0xffff0000u);
    ac[6] += __uint_as_float(v.w << 16);
    ac[7] += __uint_as_float(v.w & 0xffff0000u);
}

// ---- bucketed CSR build ----------------------------------------------------

__global__ __launch_bounds__(THREADS) void bucket_count(const int* __restrict__ dst,
                                                        int* __restrict__ btotal,
                                                        int E, int nbuck) {
    __shared__ int cnt[BSIZE];
    for (int i = threadIdx.x; i < nbuck; i += THREADS) cnt[i] = 0;
    __syncthreads();
    for (int e = blockIdx.x * THREADS + threadIdx.x; e < E; e += gridDim.x * THREADS)
        atomicAdd(&cnt[dst[e] >> BSHIFT], 1);
    __syncthreads();
    for (int i = threadIdx.x; i < nbuck; i += THREADS) {
        int c = cnt[i];
        if (c) atomicAdd(&btotal[i], c);
    }
}

__global__ __launch_bounds__(512) void bucket_scan(const int* __restrict__ btotal,
                                                   int* __restrict__ bbase,
                                                   int* __restrict__ bcursor,
                                                   int nbuck, int E) {
    __shared__ int lds[512];
    int t = threadIdx.x;
    int v = (t < nbuck) ? btotal[t] : 0;
    lds[t] = v;
    __syncthreads();
    for (int off = 1; off < 512; off <<= 1) {
        int tv = (t >= off) ? lds[t - off] : 0;
        __syncthreads();
        lds[t] += tv;
        __syncthreads();
    }
    if (t < nbuck) {
        int excl = lds[t] - v;
        bbase[t] = excl;
        bcursor[t] = excl;
    }
    if (t == 0) bbase[nbuck] = E;
}

__global__ __launch_bounds__(THREADS) void bucket_scatter(const int* __restrict__ src,
                                                          const int* __restrict__ dst,
                                                          int* __restrict__ bcursor,
                                                          int2* __restrict__ pairs, int E) {
    __shared__ int cnt[BSIZE];
    __shared__ int base[BSIZE];
    for (int i = threadIdx.x; i < BSIZE; i += THREADS) cnt[i] = 0;
    __syncthreads();
    int e0 = blockIdx.x * 2048;
    int myb[8], myrank[8], mysrc[8], mydst[8];
#pragma unroll
    for (int j = 0; j < 8; ++j) {
        int e = e0 + j * THREADS + threadIdx.x;
        myb[j] = -1;
        if (e < E) {
            int d = dst[e];
            mysrc[j] = src[e];
            mydst[j] = d;
            myb[j] = d >> BSHIFT;
            myrank[j] = atomicAdd(&cnt[myb[j]], 1);
        }
    }
    __syncthreads();
    for (int i = threadIdx.x; i < BSIZE; i += THREADS) {
        int c = cnt[i];
        base[i] = c ? atomicAdd(&bcursor[i], c) : 0;
    }
    __syncthreads();
#pragma unroll
    for (int j = 0; j < 8; ++j)
        if (myb[j] >= 0) pairs[(size_t)base[myb[j]] + myrank[j]] = make_int2(mysrc[j], mydst[j]);
}

__global__ __launch_bounds__(512) void bucket_fill(const int2* __restrict__ pairs,
                                                   const int* __restrict__ bbase,
                                                   int* __restrict__ row_start,
                                                   float* __restrict__ dinv,
                                                   int* __restrict__ esrc,
                                                   int N, int E, int nbuck) {
    __shared__ int cnt[BSIZE];
    __shared__ int scn[BSIZE];
    int b = blockIdx.x, t = threadIdx.x;
    int s = bbase[b], e = bbase[b + 1];
    cnt[t] = 0;
    __syncthreads();
    for (int i = s + t; i < e; i += 512) atomicAdd(&cnt[pairs[i].y & (BSIZE - 1)], 1);
    __syncthreads();
    int v = cnt[t];
    scn[t] = v;
    __syncthreads();
    for (int off = 1; off < 512; off <<= 1) {
        int tv = (t >= off) ? scn[t - off] : 0;
        __syncthreads();
        scn[t] += tv;
        __syncthreads();
    }
    int excl = scn[t] - v;
    int g = (b << BSHIFT) + t;
    if (g < N) {
        row_start[g] = s + excl;
        dinv[g] = rsqrtf(1.0f + (float)v);  // deg = 1 + in-degree (self-loop)
    }
    if (b == nbuck - 1 && t == 0) row_start[N] = E;
    scn[t] = excl;  // reuse as cursor
    __syncthreads();
    for (int i = s + t; i < e; i += 512) {
        int2 p = pairs[i];
        int r = atomicAdd(&scn[p.y & (BSIZE - 1)], 1);
        esrc[s + r] = p.x;
    }
}

// ---- degree counting-sort (contention-free), DESCENDING degree -------------
// A: per-block 256-bin histogram -> plain store (no global atomics).
__global__ __launch_bounds__(256) void blk_hist(const int* __restrict__ row_start,
                                                int* __restrict__ bhist, int N) {
    __shared__ int h[256];
    h[threadIdx.x] = 0;
    __syncthreads();
    int i = blockIdx.x * 256 + threadIdx.x;
    if (i < N) {
        int d = min(row_start[i + 1] - row_start[i], 255);
        atomicAdd(&h[d], 1);
    }
    __syncthreads();
    bhist[blockIdx.x * 256 + threadIdx.x] = h[threadIdx.x];
}

// B1: one block per degree value: exclusive scan down the block axis.
__global__ __launch_bounds__(512) void col_scan(int* __restrict__ bhist,
                                                int* __restrict__ colsum, int nb) {
    __shared__ int lds[512];
    int d = blockIdx.x, t = threadIdx.x;
    int v = (t < nb) ? bhist[t * 256 + d] : 0;
    lds[t] = v;
    __syncthreads();
    for (int off = 1; off < 512; off <<= 1) {
        int tv = (t >= off) ? lds[t - off] : 0;
        __syncthreads();
        lds[t] += tv;
        __syncthreads();
    }
    if (t < nb) bhist[t * 256 + d] = lds[t] - v;  // exclusive over blocks
    if (t == 0) colsum[d] = lds[511];             // column total (zero-padded)
}

// B2: degbase[d] = sum_{d' > d} colsum[d']  (descending order -> LPT dispatch)
__global__ __launch_bounds__(256) void deg_base(const int* __restrict__ colsum,
                                                int* __restrict__ degbase) {
    __shared__ int lds[256];
    int t = threadIdx.x;
    int rd = 255 - t;  // t scans degrees high -> low
    int v = colsum[rd];
    lds[t] = v;
    __syncthreads();
    for (int off = 1; off < 256; off <<= 1) {
        int tv = (t >= off) ? lds[t - off] : 0;
        __syncthreads();
        lds[t] += tv;
        __syncthreads();
    }
    degbase[rd] = lds[t] - v;  // exclusive sum of higher degrees
}

// C: scatter via LDS ranks + precomputed bases (LDS atomics only).
__global__ __launch_bounds__(256) void perm_scatter2(const int* __restrict__ row_start,
                                                     const int* __restrict__ bhist,
                                                     const int* __restrict__ degbase,
                                                     int* __restrict__ perm, int N) {
    __shared__ int h[256];
    h[threadIdx.x] = 0;
    __syncthreads();
    int i = blockIdx.x * 256 + threadIdx.x;
    if (i < N) {
        int d = min(row_start[i + 1] - row_start[i], 255);
        int rank = atomicAdd(&h[d], 1);
        perm[degbase[d] + bhist[blockIdx.x * 256 + d] + rank] = i;
    }
}

// ---- prep: all three W^T (bf16 packed) in one launch -----------------------
__device__ __forceinline__ void wt_pack(const float* W, uint4* Wtp, int C, int li) {
    int c = li >> 4, ch = li & 15;
    unsigned r[8];
#pragma unroll
    for (int j = 0; j < 8; ++j) r[j] = f2bf(W[(size_t)(ch * 8 + j) * C + c]);
    uint4 o;
    o.x = r[0] | (r[1] << 16);
    o.y = r[2] | (r[3] << 16);
    o.z = r[4] | (r[5] << 16);
    o.w = r[6] | (r[7] << 16);
    Wtp[li] = o;
}

__global__ __launch_bounds__(THREADS) void prep_wt_all(const float* __restrict__ W1,
                                                       const float* __restrict__ W2,
                                                       const float* __restrict__ W3,
                                                       uint4* __restrict__ Wt1,
                                                       uint4* __restrict__ Wt2,
                                                       uint4* __restrict__ Wt3) {
    int idx = blockIdx.x * THREADS + threadIdx.x;
    if (idx < 2048) wt_pack(W1, Wt1, 128, idx);
    else if (idx < 4096) wt_pack(W2, Wt2, 128, idx - 2048);
    else if (idx < 5120) wt_pack(W3, Wt3, 64, idx - 4096);
}

// ---- prep: z1 = bf16(dinv (.) x) -------------------------------------------
__global__ __launch_bounds__(THREADS) void prep_x(const float* __restrict__ x,
                                                  const float* __restrict__ dinv,
                                                  uint4* __restrict__ Z, int n) {
    int idx = blockIdx.x * THREADS + threadIdx.x;  // r*16 + chunk
    if (idx >= n * 16) return;
    int r = idx >> 4, c = idx & 15;
    float dv = dinv[r];
    const float* p = x + (size_t)r * 128 + c * 8;
    float4 a = *(const float4*)p;
    float4 b = *(const float4*)(p + 4);
    uint4 o;
    o.x = f2bf(a.x * dv) | (f2bf(a.y * dv) << 16);
    o.y = f2bf(a.z * dv) | (f2bf(a.w * dv) << 16);
    o.z = f2bf(b.x * dv) | (f2bf(b.y * dv) << 16);
    o.w = f2bf(b.z * dv) | (f2bf(b.w * dv) << 16);
    Z[idx] = o;
}

// ---- fused layer (perm order): gather -> LDS -> MFMA -> epilogue -----------
__global__ __launch_bounds__(THREADS) void fused_layer(const uint4* __restrict__ Z,
                                                       const uint4* __restrict__ Wt,
                                                       const int* __restrict__ row_start,
                                                       const int* __restrict__ esrc,
                                                       const float* __restrict__ dinv,
                                                       const float* __restrict__ bias,
                                                       const int* __restrict__ perm,
                                                       uint4* __restrict__ out, int n) {
    __shared__ __align__(16) uint4 ldsX[64 * 16];  // 16KB: A-tile, reused for out-stage
    __shared__ int nodes_s[64];
    int row0 = blockIdx.x * 64;
    int tid = threadIdx.x;
    int lane = tid & 15, grp = tid >> 4;

    // ---- gather phase: 16 lanes/node, 16 nodes concurrent, 4 rounds ----
    for (int round = 0; round < 4; ++round) {
        int r = round * 16 + grp;
        int gi = row0 + r;
        int nd = perm[(gi < n) ? gi : (n - 1)];  // uniform-degree within block
        if (lane == 0) nodes_s[r] = nd;
        float ac[8] = {0, 0, 0, 0, 0, 0, 0, 0};
        bf8_acc(Z[(size_t)nd * 16 + lane], ac);  // self term z[i]
        int s = row_start[nd], e = row_start[nd + 1];
        int i = s;
        for (; i + 8 <= e; i += 8) {
            int s0 = esrc[i], s1 = esrc[i + 1], s2 = esrc[i + 2], s3 = esrc[i + 3];
            int s4 = esrc[i + 4], s5 = esrc[i + 5], s6 = esrc[i + 6], s7 = esrc[i + 7];
            uint4 v0 = Z[(size_t)s0 * 16 + lane];
            uint4 v1 = Z[(size_t)s1 * 16 + lane];
            uint4 v2 = Z[(size_t)s2 * 16 + lane];
            uint4 v3 = Z[(size_t)s3 * 16 + lane];
            uint4 v4 = Z[(size_t)s4 * 16 + lane];
            uint4 v5 = Z[(size_t)s5 * 16 + lane];
            uint4 v6 = Z[(size_t)s6 * 16 + lane];
            uint4 v7 = Z[(size_t)s7 * 16 + lane];
            bf8_acc(v0, ac); bf8_acc(v1, ac); bf8_acc(v2, ac); bf8_acc(v3, ac);
            bf8_acc(v4, ac); bf8_acc(v5, ac); bf8_acc(v6, ac); bf8_acc(v7, ac);
        }
        for (; i + 4 <= e; i += 4) {
            int s0 = esrc[i], s1 = esrc[i + 1], s2 = esrc[i + 2], s3 = esrc[i + 3];
            uint4 v0 = Z[(size_t)s0 * 16 + lane];
            uint4 v1 = Z[(size_t)s1 * 16 + lane];
            uint4 v2 = Z[(size_t)s2 * 16 + lane];
            uint4 v3 = Z[(size_t)s3 * 16 + lane];
            bf8_acc(v0, ac); bf8_acc(v1, ac); bf8_acc(v2, ac); bf8_acc(v3, ac);
        }
        for (; i < e; ++i) bf8_acc(Z[(size_t)esrc[i] * 16 + lane], ac);
        float dv = dinv[nd];  // A_i = dinv_i * (sum z[src] + z[i])
        uint4 o;
        o.x = f2bf(ac[0] * dv) | (f2bf(ac[1] * dv) << 16);
        o.y = f2bf(ac[2] * dv) | (f2bf(ac[3] * dv) << 16);
        o.z = f2bf(ac[4] * dv) | (f2bf(ac[5] * dv) << 16);
        o.w = f2bf(ac[6] * dv) | (f2bf(ac[7] * dv) << 16);
        ldsX[r * 16 + (lane ^ (r & 7))] = o;
    }
    __syncthreads();

    // ---- MFMA phase: D = W^T A^T ; W read from L2-hot global ----
    int l = tid & 63, wv = tid >> 6;
    int l31 = l & 31, half = l >> 5;
    int nt = wv & 1, mt0 = (wv >> 1) * 2;
    floatx16 acc[2];
#pragma unroll
    for (int t = 0; t < 2; ++t)
#pragma unroll
        for (int q = 0; q < 16; ++q) acc[t][q] = 0.0f;
    int xrow = nt * 32 + l31, xsw = xrow & 7;
#pragma unroll
    for (int kt = 0; kt < 8; ++kt) {
        int chunk = kt * 2 + half;
        short8 xf = *(const short8*)&ldsX[xrow * 16 + (chunk ^ xsw)];
#pragma unroll
        for (int t = 0; t < 2; ++t) {
            int c = (mt0 + t) * 32 + l31;
            short8 wf = *(const short8*)&Wt[c * 16 + chunk];
            acc[t] = __builtin_amdgcn_mfma_f32_32x32x16_bf16(wf, xf, acc[t], 0, 0, 0);
        }
    }
    __syncthreads();

    // ---- epilogue: +bias, relu, x dinv(node), pack bf16 -> LDS ----
    int lrow = nt * 32 + l31;  // local row
    float dv = (row0 + lrow < n) ? dinv[nodes_s[lrow]] : 0.0f;
    char* outb = (char*)ldsX;
#pragma unroll
    for (int t = 0; t < 2; ++t) {
        int cb = (mt0 + t) * 32;
#pragma unroll
        for (int q = 0; q < 4; ++q) {
            float v[4];
#pragma unroll
            for (int m = 0; m < 4; ++m) {
                int ch = cb + 8 * q + 4 * half + m;
                float x_ = acc[t][q * 4 + m] + bias[ch];
                x_ = fmaxf(x_, 0.0f);  // relu (both fused layers use it)
                v[m] = x_ * dv;        // pre-scale for next layer's gather
            }
            uint2 pk = make_uint2(f2bf(v[0]) | (f2bf(v[1]) << 16),
                                  f2bf(v[2]) | (f2bf(v[3]) << 16));
            int chunk = (cb >> 3) + q;
            *(uint2*)(outb + lrow * 256 + ((chunk ^ (lrow & 7)) * 16) + half * 8) = pk;
        }
    }
    __syncthreads();
    int maxr = n - row0;
    if (maxr > 64) maxr = 64;
    for (int idx = tid; idx < maxr * 16; idx += THREADS) {
        int r = idx >> 4, c = idx & 15;
        out[(size_t)nodes_s[r] * 16 + c] = *(uint4*)(outb + r * 256 + ((c ^ (r & 7)) * 16));
    }
}

// ---- layer-3 GEMM: Ps = Z2 @ W3 (128 -> 64ch) ------------------------------
__global__ __launch_bounds__(THREADS) void gemm3(const uint4* __restrict__ Z,
                                                 const uint4* __restrict__ Wt,
                                                 uint4* __restrict__ out, int n) {
    __shared__ __align__(16) uint4 ldsX[64 * 16];  // 16KB
    int row0 = blockIdx.x * 64;
    int maxr = n - row0;
    if (maxr > 64) maxr = 64;
    int tid = threadIdx.x;
    for (int idx = tid; idx < 1024; idx += THREADS) {
        int r = idx >> 4, c = idx & 15;
        uint4 o = (r < maxr) ? Z[(size_t)(row0 + r) * 16 + c] : make_uint4(0, 0, 0, 0);
        ldsX[r * 16 + (c ^ (r & 7))] = o;
    }
    __syncthreads();
    int l = tid & 63, wv = tid >> 6;
    int l31 = l & 31, half = l >> 5;
    int nt = wv & 1, mt = wv >> 1;
    floatx16 acc;
#pragma unroll
    for (int q = 0; q < 16; ++q) acc[q] = 0.0f;
    int xrow = nt * 32 + l31, xsw = xrow & 7;
#pragma unroll
    for (int kt = 0; kt < 8; ++kt) {
        int chunk = kt * 2 + half;
        short8 xf = *(const short8*)&ldsX[xrow * 16 + (chunk ^ xsw)];
        int c = mt * 32 + l31;
        short8 wf = *(const short8*)&Wt[c * 16 + chunk];
        acc = __builtin_amdgcn_mfma_f32_32x32x16_bf16(wf, xf, acc, 0, 0, 0);
    }
    __syncthreads();
    int node = nt * 32 + l31;
    char* outb = (char*)ldsX;  // 64 rows x 128B
    int cb = mt * 32;
#pragma unroll
    for (int q = 0; q < 4; ++q) {
        uint2 pk = make_uint2(f2bf(acc[q * 4 + 0]) | (f2bf(acc[q * 4 + 1]) << 16),
                              f2bf(acc[q * 4 + 2]) | (f2bf(acc[q * 4 + 3]) << 16));
        int chunk = (cb >> 3) + q;
        *(uint2*)(outb + node * 128 + ((chunk ^ (node & 7)) * 16) + half * 8) = pk;
    }
    __syncthreads();
    for (int idx = tid; idx < maxr * 8; idx += THREADS) {
        int r = idx >> 3, c = idx & 7;
        out[(size_t)(row0 + r) * 8 + c] = *(uint4*)(outb + r * 128 + ((c ^ (r & 7)) * 16));
    }
}

// ---- layer-3 agg fused with mean-pool accumulation (natural node order) ----
__global__ __launch_bounds__(THREADS) void agg_pool(const uint4* __restrict__ Ps,
                                                    const int* __restrict__ row_start,
                                                    const int* __restrict__ esrc,
                                                    const float* __restrict__ dinv,
                                                    const float* __restrict__ bias,
                                                    const int* __restrict__ batch,
                                                    float* __restrict__ gsum, int n) {
    __shared__ float gpart[32][65];  // pad 65: lanes hit distinct banks
    __shared__ int used[32];
    int tid = threadIdx.x;
    int lane = tid & 7, grp = tid >> 3;
    int node = blockIdx.x * 32 + grp;
    if (tid < 32) used[tid] = 0;
    for (int idx = tid; idx < 2048; idx += THREADS) gpart[idx >> 6][idx & 63] = 0.0f;
    __syncthreads();
    int gmin = batch[blockIdx.x * 32];  // block's first node is always < n
    if (node < n) {
        float ac[8] = {0, 0, 0, 0, 0, 0, 0, 0};
        bf8_acc(Ps[(size_t)node * 8 + lane], ac);  // self
        int s = row_start[node], e = row_start[node + 1];
        int i = s;
        for (; i + 8 <= e; i += 8) {
            int s0 = esrc[i], s1 = esrc[i + 1], s2 = esrc[i + 2], s3 = esrc[i + 3];
            int s4 = esrc[i + 4], s5 = esrc[i + 5], s6 = esrc[i + 6], s7 = esrc[i + 7];
            uint4 v0 = Ps[(size_t)s0 * 8 + lane];
            uint4 v1 = Ps[(size_t)s1 * 8 + lane];
            uint4 v2 = Ps[(size_t)s2 * 8 + lane];
            uint4 v3 = Ps[(size_t)s3 * 8 + lane];
            uint4 v4 = Ps[(size_t)s4 * 8 + lane];
            uint4 v5 = Ps[(size_t)s5 * 8 + lane];
            uint4 v6 = Ps[(size_t)s6 * 8 + lane];
            uint4 v7 = Ps[(size_t)s7 * 8 + lane];
            bf8_acc(v0, ac); bf8_acc(v1, ac); bf8_acc(v2, ac); bf8_acc(v3, ac);
            bf8_acc(v4, ac); bf8_acc(v5, ac); bf8_acc(v6, ac); bf8_acc(v7, ac);
        }
        for (; i + 4 <= e; i += 4) {
            int s0 = esrc[i], s1 = esrc[i + 1], s2 = esrc[i + 2], s3 = esrc[i + 3];
            uint4 v0 = Ps[(size_t)s0 * 8 + lane];
            uint4 v1 = Ps[(size_t)s1 * 8 + lane];
            uint4 v2 = Ps[(size_t)s2 * 8 + lane];
            uint4 v3 = Ps[(size_t)s3 * 8 + lane];
            bf8_acc(v0, ac); bf8_acc(v1, ac); bf8_acc(v2, ac); bf8_acc(v3, ac);
        }
        for (; i < e; ++i) bf8_acc(Ps[(size_t)esrc[i] * 8 + lane], ac);
        float dv = dinv[node];
        float4 b0 = ((const float4*)bias)[lane * 2];
        float4 b1 = ((const float4*)bias)[lane * 2 + 1];
        float h[8];
        h[0] = fmaf(dv, ac[0], b0.x); h[1] = fmaf(dv, ac[1], b0.y);
        h[2] = fmaf(dv, ac[2], b0.z); h[3] = fmaf(dv, ac[3], b0.w);
        h[4] = fmaf(dv, ac[4], b1.x); h[5] = fmaf(dv, ac[5], b1.y);
        h[6] = fmaf(dv, ac[6], b1.z); h[7] = fmaf(dv, ac[7], b1.w);
        int g = batch[node];
        int slot = g - gmin;
        if (slot < 32) {
            if (lane == 0) used[slot] = 1;
#pragma unroll
            for (int j = 0; j < 8; ++j) atomicAdd(&gpart[slot][lane * 8 + j], h[j]);
        } else {  // only possible with empty graphs between nodes
#pragma unroll
            for (int j = 0; j < 8; ++j) atomicAdd(&gsum[(size_t)g * 64 + lane * 8 + j], h[j]);
        }
    }
    __syncthreads();
    for (int idx = tid; idx < 2048; idx += THREADS) {
        int s = idx >> 6, ch = idx & 63;
        if (used[s]) atomicAdd(&gsum[(size_t)(gmin + s) * 64 + ch], gpart[s][ch]);
    }
}

// ---- finalize: mean + FC ---------------------------------------------------
__device__ __forceinline__ int dev_lower_bound(const int* a, int n, int key) {
    int lo = 0, hi = n;
    while (lo < hi) {
        int mid = (lo + hi) >> 1;
        if (a[mid] < key) lo = mid + 1;
        else hi = mid;
    }
    return lo;
}

__global__ __launch_bounds__(128) void finalize_fc(const float* __restrict__ gsum,
                                                   const int* __restrict__ batch, int n,
                                                   const float* __restrict__ Wfc,
                                                   const float* __restrict__ bfc,
                                                   float* __restrict__ out) {
    __shared__ float gm[64 * 64];
    __shared__ float cnt[64];
    int t = threadIdx.x;
    if (t < 64)
        cnt[t] = (float)(dev_lower_bound(batch, n, t + 1) - dev_lower_bound(batch, n, t));
    __syncthreads();
    for (int i = t; i < 64 * 64; i += 128) gm[i] = gsum[i] / fmaxf(cnt[i >> 6], 1.0f);
    __syncthreads();
    int g = t >> 1, cls = t & 1;
    float acc = bfc[cls];
    for (int c = 0; c < 64; ++c) acc = fmaf(gm[g * 64 + c], Wfc[c * 2 + cls], acc);
    out[g * 2 + cls] = acc;
}

extern "C" void kernel_launch(void* const* d_in, const int* in_sizes, int n_in,
                              void* d_out, int out_size, void* d_ws, size_t ws_size,
                              hipStream_t stream) {
    const float* x    = (const float*)d_in[0];
    const int*   ei   = (const int*)d_in[1];
    const int*   batch= (const int*)d_in[2];
    const float* W1   = (const float*)d_in[3];
    const float* b1   = (const float*)d_in[4];
    const float* W2   = (const float*)d_in[5];
    const float* b2   = (const float*)d_in[6];
    const float* W3   = (const float*)d_in[7];
    const float* b3   = (const float*)d_in[8];
    const float* Wfc  = (const float*)d_in[9];
    const float* bfc  = (const float*)d_in[10];
    float* out = (float*)d_out;

    const int N = in_sizes[2];        // 100000
    const int E = in_sizes[1] / 2;    // 1600000
    const int* esrc_in = ei;          // edge_index[0]
    const int* edst_in = ei + E;      // edge_index[1]
    const int nbuck = (N + BSIZE - 1) >> BSHIFT;  // 196
    const int NB256 = (N + 255) / 256;            // 391

    // workspace layout (~86 MB)
    uint4* bufA      = (uint4*)d_ws;                  // N*16 uint4 (z, bf16 packed)
    uint4* bufB      = bufA + (size_t)N * 16;         // N*16 uint4
    uint4* bufC      = bufB + (size_t)N * 16;         // N*8 uint4 (Ps)
    int2*  pairs     = (int2*)(bufC + (size_t)N * 8); // E
    int*   esrc      = (int*)(pairs + E);             // E
    int*   row_start = esrc + E;                      // N+1
    float* dinv      = (float*)(row_start + N + 1);   // N
    int*   perm      = (int*)(dinv + N);              // N
    int*   btotal    = perm + N;                      // 512
    int*   bbase     = btotal + 512;                  // 513
    int*   bcursor   = bbase + 513;                   // 512
    int*   colsum    = bcursor + 512;                 // 256
    int*   degbase   = colsum + 256;                  // 256
    int*   bhist     = degbase + 256;                 // NB256*256 (<=131072)
    float* gsum      = (float*)(bhist + 131072);      // 64*64
    uint4* Wt1       = (uint4*)(gsum + 64 * 64);      // 2048
    uint4* Wt2       = Wt1 + 2048;                    // 2048
    uint4* Wt3       = Wt2 + 2048;                    // 1024

    // ---- CSR build + degree sort + prep ----
    hipMemsetAsync(btotal, 0, 512 * sizeof(int), stream);
    hipMemsetAsync(gsum, 0, 64 * 64 * sizeof(float), stream);
    bucket_count<<<512, THREADS, 0, stream>>>(edst_in, btotal, E, nbuck);
    bucket_scan<<<1, 512, 0, stream>>>(btotal, bbase, bcursor, nbuck, E);
    bucket_scatter<<<(E + 2047) / 2048, THREADS, 0, stream>>>(esrc_in, edst_in, bcursor, pairs, E);
    bucket_fill<<<nbuck, 512, 0, stream>>>(pairs, bbase, row_start, dinv, esrc, N, E, nbuck);
    blk_hist<<<NB256, 256, 0, stream>>>(row_start, bhist, N);
    col_scan<<<256, 512, 0, stream>>>(bhist, colsum, NB256);
    deg_base<<<1, 256, 0, stream>>>(colsum, degbase);
    perm_scatter2<<<NB256, 256, 0, stream>>>(row_start, bhist, degbase, perm, N);
    prep_wt_all<<<20, THREADS, 0, stream>>>(W1, W2, W3, Wt1, Wt2, Wt3);
    prep_x<<<(N * 16 + THREADS - 1) / THREADS, THREADS, 0, stream>>>(x, dinv, bufA, N);

    const int GB = (N + 63) / 64;

    // ---- layers (agg-commuted, LPT degree-balanced) ----
    fused_layer<<<GB, THREADS, 0, stream>>>(bufA, Wt1, row_start, esrc, dinv, b1, perm, bufB, N);
    fused_layer<<<GB, THREADS, 0, stream>>>(bufB, Wt2, row_start, esrc, dinv, b2, perm, bufA, N);
    gemm3<<<GB, THREADS, 0, stream>>>(bufA, Wt3, bufC, N);
    agg_pool<<<(N + 31) / 32, THREADS, 0, stream>>>(bufC, row_start, esrc, dinv, b3, batch, gsum, N);

    // ---- finalize ----
    finalize_fc<<<1, 128, 0, stream>>>(gsum, batch, N, Wfc, bfc, out);
}

// Round 9
// 433.431 us; speedup vs baseline: 1.6884x; 1.0238x over previous
//
#include <hip/hip_runtime.h>
#include <hip/hip_bf16.h>

// ---------------------------------------------------------------------------
// GCN via agg-commute: agg(XW) == agg(X)W. z = dinv (.) h stored bf16.
// Fused layer: A_i = dinv_i(sum z[src] + z[i]) -> LDS -> MFMA A@W -> +b, relu,
// x dinv -> bf16. Layer3: P = z2@W3, then agg64 fused with mean-pool.
// R9: dropped degree-perm machinery (R6 440.7 vs R8 443.7 — measured zero),
//     packed CSR pairs (src<<9|dst&511: halves scatter/fill pair bytes),
//     gsum zero folded into bucket_scan. 19 -> 12 dispatches.
// ---------------------------------------------------------------------------

#define THREADS 256
#define BSHIFT 9
#define BSIZE 512

typedef __attribute__((ext_vector_type(8))) short short8;
typedef __attribute__((ext_vector_type(16))) float floatx16;

__device__ __forceinline__ unsigned f2bf(float f) {  // fp32 -> bf16 bits, RNE
    unsigned u = __float_as_uint(f);
    return (u + 0x7fffu + ((u >> 16) & 1u)) >> 16;
}

__device__ __forceinline__ void bf8_acc(uint4 v, float* ac) {
    ac[0] += __uint_as_float(v.x << 16);
    ac[1] += __uint_as_float(v.x & 0xffff0000u);
    ac[2] += __uint_as_float(v.y << 16);
    ac[3] += __uint_as_float(v.y & 0xffff0000u);
    ac[4] += __uint_as_float(v.z << 16);
    ac[5] += __uint_as_float(v.z & 0xffff0000u);
    ac[6] += __uint_as_float(v.w << 16);
    ac[7] += __uint_as_float(v.w & 0xffff0000u);
}

// ---- bucketed CSR build ----------------------------------------------------

__global__ __launch_bounds__(THREADS) void bucket_count(const int* __restrict__ dst,
                                                        int* __restrict__ btotal,
                                                        int E, int nbuck) {
    __shared__ int cnt[BSIZE];
    for (int i = threadIdx.x; i < nbuck; i += THREADS) cnt[i] = 0;
    __syncthreads();
    for (int e = blockIdx.x * THREADS + threadIdx.x; e < E; e += gridDim.x * THREADS)
        atomicAdd(&cnt[dst[e] >> BSHIFT], 1);
    __syncthreads();
    for (int i = threadIdx.x; i < nbuck; i += THREADS) {
        int c = cnt[i];
        if (c) atomicAdd(&btotal[i], c);
    }
}

// also zeros gsum (idle threads, 1-block kernel)
__global__ __launch_bounds__(512) void bucket_scan(const int* __restrict__ btotal,
                                                   int* __restrict__ bbase,
                                                   int* __restrict__ bcursor,
                                                   float* __restrict__ gsum,
                                                   int nbuck, int E) {
    __shared__ int lds[512];
    int t = threadIdx.x;
    for (int i = t; i < 64 * 64; i += 512) gsum[i] = 0.0f;
    int v = (t < nbuck) ? btotal[t] : 0;
    lds[t] = v;
    __syncthreads();
    for (int off = 1; off < 512; off <<= 1) {
        int tv = (t >= off) ? lds[t - off] : 0;
        __syncthreads();
        lds[t] += tv;
        __syncthreads();
    }
    if (t < nbuck) {
        int excl = lds[t] - v;
        bbase[t] = excl;
        bcursor[t] = excl;
    }
    if (t == 0) bbase[nbuck] = E;
}

// chunk = 2048 edges/block; packed pair = (src<<9) | (dst & 511)
__global__ __launch_bounds__(THREADS) void bucket_scatter(const int* __restrict__ src,
                                                          const int* __restrict__ dst,
                                                          int* __restrict__ bcursor,
                                                          int* __restrict__ pairs, int E) {
    __shared__ int cnt[BSIZE];
    __shared__ int base[BSIZE];
    for (int i = threadIdx.x; i < BSIZE; i += THREADS) cnt[i] = 0;
    __syncthreads();
    int e0 = blockIdx.x * 2048;
    int myb[8], myrank[8], mypk[8];
#pragma unroll
    for (int j = 0; j < 8; ++j) {
        int e = e0 + j * THREADS + threadIdx.x;
        myb[j] = -1;
        if (e < E) {
            int d = dst[e];
            mypk[j] = (src[e] << BSHIFT) | (d & (BSIZE - 1));
            myb[j] = d >> BSHIFT;
            myrank[j] = atomicAdd(&cnt[myb[j]], 1);
        }
    }
    __syncthreads();
    for (int i = threadIdx.x; i < BSIZE; i += THREADS) {
        int c = cnt[i];
        base[i] = c ? atomicAdd(&bcursor[i], c) : 0;
    }
    __syncthreads();
#pragma unroll
    for (int j = 0; j < 8; ++j)
        if (myb[j] >= 0) pairs[(size_t)base[myb[j]] + myrank[j]] = mypk[j];
}

// one block per bucket: local count/scan -> row_start+dinv; local cursor -> esrc.
__global__ __launch_bounds__(512) void bucket_fill(const int* __restrict__ pairs,
                                                   const int* __restrict__ bbase,
                                                   int* __restrict__ row_start,
                                                   float* __restrict__ dinv,
                                                   int* __restrict__ esrc,
                                                   int N, int E, int nbuck) {
    __shared__ int cnt[BSIZE];
    __shared__ int scn[BSIZE];
    int b = blockIdx.x, t = threadIdx.x;
    int s = bbase[b], e = bbase[b + 1];
    cnt[t] = 0;
    __syncthreads();
    for (int i = s + t; i < e; i += 512) atomicAdd(&cnt[pairs[i] & (BSIZE - 1)], 1);
    __syncthreads();
    int v = cnt[t];
    scn[t] = v;
    __syncthreads();
    for (int off = 1; off < 512; off <<= 1) {
        int tv = (t >= off) ? scn[t - off] : 0;
        __syncthreads();
        scn[t] += tv;
        __syncthreads();
    }
    int excl = scn[t] - v;
    int g = (b << BSHIFT) + t;
    if (g < N) {
        row_start[g] = s + excl;
        dinv[g] = rsqrtf(1.0f + (float)v);  // deg = 1 + in-degree (self-loop)
    }
    if (b == nbuck - 1 && t == 0) row_start[N] = E;
    scn[t] = excl;  // reuse as cursor
    __syncthreads();
    for (int i = s + t; i < e; i += 512) {
        int p = pairs[i];
        int r = atomicAdd(&scn[p & (BSIZE - 1)], 1);
        esrc[s + r] = ((unsigned)p) >> BSHIFT;
    }
}

// ---- prep: all three W^T (bf16 packed) in one launch -----------------------
__device__ __forceinline__ void wt_pack(const float* W, uint4* Wtp, int C, int li) {
    int c = li >> 4, ch = li & 15;
    unsigned r[8];
#pragma unroll
    for (int j = 0; j < 8; ++j) r[j] = f2bf(W[(size_t)(ch * 8 + j) * C + c]);
    uint4 o;
    o.x = r[0] | (r[1] << 16);
    o.y = r[2] | (r[3] << 16);
    o.z = r[4] | (r[5] << 16);
    o.w = r[6] | (r[7] << 16);
    Wtp[li] = o;
}

__global__ __launch_bounds__(THREADS) void prep_wt_all(const float* __restrict__ W1,
                                                       const float* __restrict__ W2,
                                                       const float* __restrict__ W3,
                                                       uint4* __restrict__ Wt1,
                                                       uint4* __restrict__ Wt2,
                                                       uint4* __restrict__ Wt3) {
    int idx = blockIdx.x * THREADS + threadIdx.x;
    if (idx < 2048) wt_pack(W1, Wt1, 128, idx);
    else if (idx < 4096) wt_pack(W2, Wt2, 128, idx - 2048);
    else if (idx < 5120) wt_pack(W3, Wt3, 64, idx - 4096);
}

// ---- prep: z1 = bf16(dinv (.) x) -------------------------------------------
__global__ __launch_bounds__(THREADS) void prep_x(const float* __restrict__ x,
                                                  const float* __restrict__ dinv,
                                                  uint4* __restrict__ Z, int n) {
    int idx = blockIdx.x * THREADS + threadIdx.x;  // r*16 + chunk
    if (idx >= n * 16) return;
    int r = idx >> 4, c = idx & 15;
    float dv = dinv[r];
    const float* p = x + (size_t)r * 128 + c * 8;
    float4 a = *(const float4*)p;
    float4 b = *(const float4*)(p + 4);
    uint4 o;
    o.x = f2bf(a.x * dv) | (f2bf(a.y * dv) << 16);
    o.y = f2bf(a.z * dv) | (f2bf(a.w * dv) << 16);
    o.z = f2bf(b.x * dv) | (f2bf(b.y * dv) << 16);
    o.w = f2bf(b.z * dv) | (f2bf(b.w * dv) << 16);
    Z[idx] = o;
}

// ---- fused layer: gather -> LDS -> MFMA -> epilogue (natural order) --------
__global__ __launch_bounds__(THREADS) void fused_layer(const uint4* __restrict__ Z,
                                                       const uint4* __restrict__ Wt,
                                                       const int* __restrict__ row_start,
                                                       const int* __restrict__ esrc,
                                                       const float* __restrict__ dinv,
                                                       const float* __restrict__ bias,
                                                       uint4* __restrict__ out, int n) {
    __shared__ __align__(16) uint4 ldsX[64 * 16];  // 16KB: A-tile, reused for out-stage
    int row0 = blockIdx.x * 64;
    int maxr = n - row0;
    if (maxr > 64) maxr = 64;
    int tid = threadIdx.x;
    int lane = tid & 15, grp = tid >> 4;

    // ---- gather phase: 16 lanes/node, 16 nodes concurrent, 4 rounds ----
    for (int round = 0; round < 4; ++round) {
        int r = round * 16 + grp;
        int node = row0 + r;
        int nd = (node < n) ? node : (n - 1);
        float ac[8] = {0, 0, 0, 0, 0, 0, 0, 0};
        bf8_acc(Z[(size_t)nd * 16 + lane], ac);  // self term z[i]
        int s = row_start[nd], e = row_start[nd + 1];
        int i = s;
        for (; i + 8 <= e; i += 8) {
            int s0 = esrc[i], s1 = esrc[i + 1], s2 = esrc[i + 2], s3 = esrc[i + 3];
            int s4 = esrc[i + 4], s5 = esrc[i + 5], s6 = esrc[i + 6], s7 = esrc[i + 7];
            uint4 v0 = Z[(size_t)s0 * 16 + lane];
            uint4 v1 = Z[(size_t)s1 * 16 + lane];
            uint4 v2 = Z[(size_t)s2 * 16 + lane];
            uint4 v3 = Z[(size_t)s3 * 16 + lane];
            uint4 v4 = Z[(size_t)s4 * 16 + lane];
            uint4 v5 = Z[(size_t)s5 * 16 + lane];
            uint4 v6 = Z[(size_t)s6 * 16 + lane];
            uint4 v7 = Z[(size_t)s7 * 16 + lane];
            bf8_acc(v0, ac); bf8_acc(v1, ac); bf8_acc(v2, ac); bf8_acc(v3, ac);
            bf8_acc(v4, ac); bf8_acc(v5, ac); bf8_acc(v6, ac); bf8_acc(v7, ac);
        }
        for (; i + 4 <= e; i += 4) {
            int s0 = esrc[i], s1 = esrc[i + 1], s2 = esrc[i + 2], s3 = esrc[i + 3];
            uint4 v0 = Z[(size_t)s0 * 16 + lane];
            uint4 v1 = Z[(size_t)s1 * 16 + lane];
            uint4 v2 = Z[(size_t)s2 * 16 + lane];
            uint4 v3 = Z[(size_t)s3 * 16 + lane];
            bf8_acc(v0, ac); bf8_acc(v1, ac); bf8_acc(v2, ac); bf8_acc(v3, ac);
        }
        for (; i < e; ++i) bf8_acc(Z[(size_t)esrc[i] * 16 + lane], ac);
        float dv = dinv[nd];  // A_i = dinv_i * (sum z[src] + z[i])
        uint4 o;
        o.x = f2bf(ac[0] * dv) | (f2bf(ac[1] * dv) << 16);
        o.y = f2bf(ac[2] * dv) | (f2bf(ac[3] * dv) << 16);
        o.z = f2bf(ac[4] * dv) | (f2bf(ac[5] * dv) << 16);
        o.w = f2bf(ac[6] * dv) | (f2bf(ac[7] * dv) << 16);
        ldsX[r * 16 + (lane ^ (r & 7))] = o;
    }
    __syncthreads();

    // ---- MFMA phase: D = W^T A^T ; W read from L2-hot global ----
    int l = tid & 63, wv = tid >> 6;
    int l31 = l & 31, half = l >> 5;
    int nt = wv & 1, mt0 = (wv >> 1) * 2;
    floatx16 acc[2];
#pragma unroll
    for (int t = 0; t < 2; ++t)
#pragma unroll
        for (int q = 0; q < 16; ++q) acc[t][q] = 0.0f;
    int xrow = nt * 32 + l31, xsw = xrow & 7;
#pragma unroll
    for (int kt = 0; kt < 8; ++kt) {
        int chunk = kt * 2 + half;
        short8 xf = *(const short8*)&ldsX[xrow * 16 + (chunk ^ xsw)];
#pragma unroll
        for (int t = 0; t < 2; ++t) {
            int c = (mt0 + t) * 32 + l31;
            short8 wf = *(const short8*)&Wt[c * 16 + chunk];
            acc[t] = __builtin_amdgcn_mfma_f32_32x32x16_bf16(wf, xf, acc[t], 0, 0, 0);
        }
    }
    __syncthreads();

    // ---- epilogue: +bias, relu, x dinv(node), pack bf16 -> LDS -> store ----
    int node = nt * 32 + l31;
    float dv = (node < maxr) ? dinv[row0 + node] : 0.0f;
    char* outb = (char*)ldsX;
#pragma unroll
    for (int t = 0; t < 2; ++t) {
        int cb = (mt0 + t) * 32;
#pragma unroll
        for (int q = 0; q < 4; ++q) {
            float v[4];
#pragma unroll
            for (int m = 0; m < 4; ++m) {
                int ch = cb + 8 * q + 4 * half + m;
                float x_ = acc[t][q * 4 + m] + bias[ch];
                x_ = fmaxf(x_, 0.0f);  // relu (both fused layers use it)
                v[m] = x_ * dv;        // pre-scale for next layer's gather
            }
            uint2 pk = make_uint2(f2bf(v[0]) | (f2bf(v[1]) << 16),
                                  f2bf(v[2]) | (f2bf(v[3]) << 16));
            int chunk = (cb >> 3) + q;
            *(uint2*)(outb + node * 256 + ((chunk ^ (node & 7)) * 16) + half * 8) = pk;
        }
    }
    __syncthreads();
    for (int idx = tid; idx < maxr * 16; idx += THREADS) {
        int r = idx >> 4, c = idx & 15;
        out[(size_t)(row0 + r) * 16 + c] = *(uint4*)(outb + r * 256 + ((c ^ (r & 7)) * 16));
    }
}

// ---- layer-3 GEMM: Ps = Z2 @ W3 (128 -> 64ch) ------------------------------
__global__ __launch_bounds__(THREADS) void gemm3(const uint4* __restrict__ Z,
                                                 const uint4* __restrict__ Wt,
                                                 uint4* __restrict__ out, int n) {
    __shared__ __align__(16) uint4 ldsX[64 * 16];  // 16KB
    int row0 = blockIdx.x * 64;
    int maxr = n - row0;
    if (maxr > 64) maxr = 64;
    int tid = threadIdx.x;
    for (int idx = tid; idx < 1024; idx += THREADS) {
        int r = idx >> 4, c = idx & 15;
        uint4 o = (r < maxr) ? Z[(size_t)(row0 + r) * 16 + c] : make_uint4(0, 0, 0, 0);
        ldsX[r * 16 + (c ^ (r & 7))] = o;
    }
    __syncthreads();
    int l = tid & 63, wv = tid >> 6;
    int l31 = l & 31, half = l >> 5;
    int nt = wv & 1, mt = wv >> 1;
    floatx16 acc;
#pragma unroll
    for (int q = 0; q < 16; ++q) acc[q] = 0.0f;
    int xrow = nt * 32 + l31, xsw = xrow & 7;
#pragma unroll
    for (int kt = 0; kt < 8; ++kt) {
        int chunk = kt * 2 + half;
        short8 xf = *(const short8*)&ldsX[xrow * 16 + (chunk ^ xsw)];
        int c = mt * 32 + l31;
        short8 wf = *(const short8*)&Wt[c * 16 + chunk];
        acc = __builtin_amdgcn_mfma_f32_32x32x16_bf16(wf, xf, acc, 0, 0, 0);
    }
    __syncthreads();
    int node = nt * 32 + l31;
    char* outb = (char*)ldsX;  // 64 rows x 128B
    int cb = mt * 32;
#pragma unroll
    for (int q = 0; q < 4; ++q) {
        uint2 pk = make_uint2(f2bf(acc[q * 4 + 0]) | (f2bf(acc[q * 4 + 1]) << 16),
                              f2bf(acc[q * 4 + 2]) | (f2bf(acc[q * 4 + 3]) << 16));
        int chunk = (cb >> 3) + q;
        *(uint2*)(outb + node * 128 + ((chunk ^ (node & 7)) * 16) + half * 8) = pk;
    }
    __syncthreads();
    for (int idx = tid; idx < maxr * 8; idx += THREADS) {
        int r = idx >> 3, c = idx & 7;
        out[(size_t)(row0 + r) * 8 + c] = *(uint4*)(outb + r * 128 + ((c ^ (r & 7)) * 16));
    }
}

// ---- layer-3 agg fused with mean-pool accumulation -------------------------
__global__ __launch_bounds__(THREADS) void agg_pool(const uint4* __restrict__ Ps,
                                                    const int* __restrict__ row_start,
                                                    const int* __restrict__ esrc,
                                                    const float* __restrict__ dinv,
                                                    const float* __restrict__ bias,
                                                    const int* __restrict__ batch,
                                                    float* __restrict__ gsum, int n) {
    __shared__ float gpart[32][65];  // pad 65: lanes hit distinct banks
    __shared__ int used[32];
    int tid = threadIdx.x;
    int lane = tid & 7, grp = tid >> 3;
    int node = blockIdx.x * 32 + grp;
    if (tid < 32) used[tid] = 0;
    for (int idx = tid; idx < 2048; idx += THREADS) gpart[idx >> 6][idx & 63] = 0.0f;
    __syncthreads();
    int gmin = batch[blockIdx.x * 32];  // block's first node is always < n
    if (node < n) {
        float ac[8] = {0, 0, 0, 0, 0, 0, 0, 0};
        bf8_acc(Ps[(size_t)node * 8 + lane], ac);  // self
        int s = row_start[node], e = row_start[node + 1];
        int i = s;
        for (; i + 8 <= e; i += 8) {
            int s0 = esrc[i], s1 = esrc[i + 1], s2 = esrc[i + 2], s3 = esrc[i + 3];
            int s4 = esrc[i + 4], s5 = esrc[i + 5], s6 = esrc[i + 6], s7 = esrc[i + 7];
            uint4 v0 = Ps[(size_t)s0 * 8 + lane];
            uint4 v1 = Ps[(size_t)s1 * 8 + lane];
            uint4 v2 = Ps[(size_t)s2 * 8 + lane];
            uint4 v3 = Ps[(size_t)s3 * 8 + lane];
            uint4 v4 = Ps[(size_t)s4 * 8 + lane];
            uint4 v5 = Ps[(size_t)s5 * 8 + lane];
            uint4 v6 = Ps[(size_t)s6 * 8 + lane];
            uint4 v7 = Ps[(size_t)s7 * 8 + lane];
            bf8_acc(v0, ac); bf8_acc(v1, ac); bf8_acc(v2, ac); bf8_acc(v3, ac);
            bf8_acc(v4, ac); bf8_acc(v5, ac); bf8_acc(v6, ac); bf8_acc(v7, ac);
        }
        for (; i + 4 <= e; i += 4) {
            int s0 = esrc[i], s1 = esrc[i + 1], s2 = esrc[i + 2], s3 = esrc[i + 3];
            uint4 v0 = Ps[(size_t)s0 * 8 + lane];
            uint4 v1 = Ps[(size_t)s1 * 8 + lane];
            uint4 v2 = Ps[(size_t)s2 * 8 + lane];
            uint4 v3 = Ps[(size_t)s3 * 8 + lane];
            bf8_acc(v0, ac); bf8_acc(v1, ac); bf8_acc(v2, ac); bf8_acc(v3, ac);
        }
        for (; i < e; ++i) bf8_acc(Ps[(size_t)esrc[i] * 8 + lane], ac);
        float dv = dinv[node];
        float4 b0 = ((const float4*)bias)[lane * 2];
        float4 b1 = ((const float4*)bias)[lane * 2 + 1];
        float h[8];
        h[0] = fmaf(dv, ac[0], b0.x); h[1] = fmaf(dv, ac[1], b0.y);
        h[2] = fmaf(dv, ac[2], b0.z); h[3] = fmaf(dv, ac[3], b0.w);
        h[4] = fmaf(dv, ac[4], b1.x); h[5] = fmaf(dv, ac[5], b1.y);
        h[6] = fmaf(dv, ac[6], b1.z); h[7] = fmaf(dv, ac[7], b1.w);
        int g = batch[node];
        int slot = g - gmin;
        if (slot < 32) {
            if (lane == 0) used[slot] = 1;
#pragma unroll
            for (int j = 0; j < 8; ++j) atomicAdd(&gpart[slot][lane * 8 + j], h[j]);
        } else {  // only possible with empty graphs between nodes
#pragma unroll
            for (int j = 0; j < 8; ++j) atomicAdd(&gsum[(size_t)g * 64 + lane * 8 + j], h[j]);
        }
    }
    __syncthreads();
    for (int idx = tid; idx < 2048; idx += THREADS) {
        int s = idx >> 6, ch = idx & 63;
        if (used[s]) atomicAdd(&gsum[(size_t)(gmin + s) * 64 + ch], gpart[s][ch]);
    }
}

// ---- finalize: mean + FC ---------------------------------------------------
__device__ __forceinline__ int dev_lower_bound(const int* a, int n, int key) {
    int lo = 0, hi = n;
    while (lo < hi) {
        int mid = (lo + hi) >> 1;
        if (a[mid] < key) lo = mid + 1;
        else hi = mid;
    }
    return lo;
}

__global__ __launch_bounds__(128) void finalize_fc(const float* __restrict__ gsum,
                                                   const int* __restrict__ batch, int n,
                                                   const float* __restrict__ Wfc,
                                                   const float* __restrict__ bfc,
                                                   float* __restrict__ out) {
    __shared__ float gm[64 * 64];
    __shared__ float cnt[64];
    int t = threadIdx.x;
    if (t < 64)
        cnt[t] = (float)(dev_lower_bound(batch, n, t + 1) - dev_lower_bound(batch, n, t));
    __syncthreads();
    for (int i = t; i < 64 * 64; i += 128) gm[i] = gsum[i] / fmaxf(cnt[i >> 6], 1.0f);
    __syncthreads();
    int g = t >> 1, cls = t & 1;
    float acc = bfc[cls];
    for (int c = 0; c < 64; ++c) acc = fmaf(gm[g * 64 + c], Wfc[c * 2 + cls], acc);
    out[g * 2 + cls] = acc;
}

extern "C" void kernel_launch(void* const* d_in, const int* in_sizes, int n_in,
                              void* d_out, int out_size, void* d_ws, size_t ws_size,
                              hipStream_t stream) {
    const float* x    = (const float*)d_in[0];
    const int*   ei   = (const int*)d_in[1];
    const int*   batch= (const int*)d_in[2];
    const float* W1   = (const float*)d_in[3];
    const float* b1   = (const float*)d_in[4];
    const float* W2   = (const float*)d_in[5];
    const float* b2   = (const float*)d_in[6];
    const float* W3   = (const float*)d_in[7];
    const float* b3   = (const float*)d_in[8];
    const float* Wfc  = (const float*)d_in[9];
    const float* bfc  = (const float*)d_in[10];
    float* out = (float*)d_out;

    const int N = in_sizes[2];        // 100000
    const int E = in_sizes[1] / 2;    // 1600000
    const int* esrc_in = ei;          // edge_index[0]
    const int* edst_in = ei + E;      // edge_index[1]
    const int nbuck = (N + BSIZE - 1) >> BSHIFT;  // 196

    // workspace layout (~78 MB)
    uint4* bufA      = (uint4*)d_ws;                  // N*16 uint4 (z, bf16 packed)
    uint4* bufB      = bufA + (size_t)N * 16;         // N*16 uint4
    uint4* bufC      = bufB + (size_t)N * 16;         // N*8 uint4 (Ps)
    int*   pairs     = (int*)(bufC + (size_t)N * 8);  // E (packed src<<9|dst&511)
    int*   esrc      = pairs + E;                     // E
    int*   row_start = esrc + E;                      // N+1
    float* dinv      = (float*)(row_start + N + 1);   // N
    int*   btotal    = (int*)(dinv + N);              // 512
    int*   bbase     = btotal + 512;                  // 513
    int*   bcursor   = bbase + 513;                   // 512
    float* gsum      = (float*)(bcursor + 512);       // 64*64
    uint4* Wt1       = (uint4*)(gsum + 64 * 64);      // 2048
    uint4* Wt2       = Wt1 + 2048;                    // 2048
    uint4* Wt3       = Wt2 + 2048;                    // 1024

    // ---- CSR build + prep (12 dispatches total) ----
    hipMemsetAsync(btotal, 0, 512 * sizeof(int), stream);
    bucket_count<<<512, THREADS, 0, stream>>>(edst_in, btotal, E, nbuck);
    bucket_scan<<<1, 512, 0, stream>>>(btotal, bbase, bcursor, gsum, nbuck, E);
    bucket_scatter<<<(E + 2047) / 2048, THREADS, 0, stream>>>(esrc_in, edst_in, bcursor, pairs, E);
    bucket_fill<<<nbuck, 512, 0, stream>>>(pairs, bbase, row_start, dinv, esrc, N, E, nbuck);
    prep_wt_all<<<20, THREADS, 0, stream>>>(W1, W2, W3, Wt1, Wt2, Wt3);
    prep_x<<<(N * 16 + THREADS - 1) / THREADS, THREADS, 0, stream>>>(x, dinv, bufA, N);

    const int GB = (N + 63) / 64;

    // ---- layers (agg-commuted) ----
    fused_layer<<<GB, THREADS, 0, stream>>>(bufA, Wt1, row_start, esrc, dinv, b1, bufB, N);
    fused_layer<<<GB, THREADS, 0, stream>>>(bufB, Wt2, row_start, esrc, dinv, b2, bufA, N);
    gemm3<<<GB, THREADS, 0, stream>>>(bufA, Wt3, bufC, N);
    agg_pool<<<(N + 31) / 32, THREADS, 0, stream>>>(bufC, row_start, esrc, dinv, b3, batch, gsum, N);

    // ---- finalize ----
    finalize_fc<<<1, 128, 0, stream>>>(gsum, batch, N, Wfc, bfc, out);
}